// Round 8
// baseline (96.746 us; speedup 1.0000x reference)
//
#include <hip/hip_runtime.h>
#include <math.h>

#define NN 4096
#define BB 8
#define NV4 (NN / 4)   // float4 per row = 1024
#define NCH 16         // chunks: lane covers idx = c*64 + lane

// Wave = 2 rows x ALL 4 gates (acc[4][2][8]); block = 4 waves = 8 rows.
// No LDS, no barriers. Matrix streams (HBM-latency) register-prefetched one
// chunk ahead; x/h chunks (256 KB, L2-resident) loaded on demand. GRU
// epilogue entirely in-wave after a full butterfly.
// R6 post-mortem: all pipe floors ~7-21us vs 56us measured with HBM idle
// 75% -> latency/sync structure, not bandwidth; so remove ALL sync and
// maximize per-wave load ILP.
__global__ __launch_bounds__(256, 2) void attgru_fused_kernel(
    const float* __restrict__ x,   const float* __restrict__ h,
    const float* __restrict__ adj, const float* __restrict__ Whr,
    const float* __restrict__ bhr, const float* __restrict__ Whz,
    const float* __restrict__ bhz, const float* __restrict__ Whn,
    const float* __restrict__ bhn, float* __restrict__ out)
{
    const int lane = threadIdx.x & 63;
    const int wave = threadIdx.x >> 6;            // 0..3
    const int row0 = blockIdx.x * 8 + wave * 2;   // 2 rows per wave

    const float4* x4 = reinterpret_cast<const float4*>(x);
    const float4* h4 = reinterpret_cast<const float4*>(h);
    const size_t rb = (size_t)row0 * NV4;
    const float4* A = reinterpret_cast<const float4*>(adj) + rb;
    const float4* R = reinterpret_cast<const float4*>(Whr) + rb;
    const float4* Z = reinterpret_cast<const float4*>(Whz) + rb;
    const float4* G = reinterpret_cast<const float4*>(Whn) + rb;

    float acc[4][2][BB];
#pragma unroll
    for (int g = 0; g < 4; ++g)
#pragma unroll
        for (int r = 0; r < 2; ++r)
#pragma unroll
            for (int b = 0; b < BB; ++b) acc[g][r][b] = 0.f;

    // matrix regs, prefetched one chunk ahead (8 float4 = 32 VGPR)
    float4 mA[2], mR[2], mZ[2], mG[2];
#pragma unroll
    for (int r = 0; r < 2; ++r) {
        mA[r] = A[r * NV4 + lane];
        mR[r] = R[r * NV4 + lane];
        mZ[r] = Z[r * NV4 + lane];
        mG[r] = G[r * NV4 + lane];
    }

    for (int c = 0; c < NCH; ++c) {
        const int idx = c * 64 + lane;
        const bool more = (c + 1 < NCH);
        // ---- issue next chunk's matrix loads first (HBM latency path) ----
        float4 nA[2], nR[2], nZ[2], nG[2];
        if (more) {
            const int nidx = idx + 64;
#pragma unroll
            for (int r = 0; r < 2; ++r) {
                nA[r] = A[r * NV4 + nidx];
                nR[r] = R[r * NV4 + nidx];
                nZ[r] = Z[r * NV4 + nidx];
                nG[r] = G[r * NV4 + nidx];
            }
        }
        // ---- phase X: agg gate (x chunk, L2-hot) ----
#pragma unroll
        for (int b = 0; b < BB; ++b) {
            const float4 v = x4[b * NV4 + idx];
            acc[0][0][b] += mA[0].x*v.x + mA[0].y*v.y + mA[0].z*v.z + mA[0].w*v.w;
            acc[0][1][b] += mA[1].x*v.x + mA[1].y*v.y + mA[1].z*v.z + mA[1].w*v.w;
        }
        // ---- phase H: r/z/n gates (h chunk, L2-hot) ----
#pragma unroll
        for (int b = 0; b < BB; ++b) {
            const float4 v = h4[b * NV4 + idx];
            acc[1][0][b] += mR[0].x*v.x + mR[0].y*v.y + mR[0].z*v.z + mR[0].w*v.w;
            acc[1][1][b] += mR[1].x*v.x + mR[1].y*v.y + mR[1].z*v.z + mR[1].w*v.w;
            acc[2][0][b] += mZ[0].x*v.x + mZ[0].y*v.y + mZ[0].z*v.z + mZ[0].w*v.w;
            acc[2][1][b] += mZ[1].x*v.x + mZ[1].y*v.y + mZ[1].z*v.z + mZ[1].w*v.w;
            acc[3][0][b] += mG[0].x*v.x + mG[0].y*v.y + mG[0].z*v.z + mG[0].w*v.w;
            acc[3][1][b] += mG[1].x*v.x + mG[1].y*v.y + mG[1].z*v.z + mG[1].w*v.w;
        }
        // ---- rotate prefetched matrix regs ----
        if (more) {
#pragma unroll
            for (int r = 0; r < 2; ++r) {
                mA[r] = nA[r]; mR[r] = nR[r]; mZ[r] = nZ[r]; mG[r] = nG[r];
            }
        }
    }

    // full-wave butterfly: all lanes end with complete sums
#pragma unroll
    for (int off = 32; off >= 1; off >>= 1)
#pragma unroll
        for (int g = 0; g < 4; ++g)
#pragma unroll
            for (int r = 0; r < 2; ++r)
#pragma unroll
                for (int b = 0; b < BB; ++b)
                    acc[g][r][b] += __shfl_xor(acc[g][r][b], off);

    // in-wave epilogue: lanes 0..15 -> (row r, batch b)
    if (lane < 16) {
        const int r = lane >> 3, b = lane & 7;
        const int row = row0 + r;
        const float agg = acc[0][r][b];
        const float rg = 1.f / (1.f + __expf(-(agg + acc[1][r][b] + bhr[row])));
        const float zg = 1.f / (1.f + __expf(-(agg + acc[2][r][b] + bhz[row])));
        const float ng = tanhf(agg + rg * (acc[3][r][b] + bhn[row]));
        const float hv = h[b * NN + row];
        out[b * NN + row] = (1.f - zg) * ng + zg * hv;
    }
}

extern "C" void kernel_launch(void* const* d_in, const int* in_sizes, int n_in,
                              void* d_out, int out_size, void* d_ws, size_t ws_size,
                              hipStream_t stream) {
    const float* x   = (const float*)d_in[0];
    const float* h   = (const float*)d_in[1];
    const float* adj = (const float*)d_in[2];
    const float* Whr = (const float*)d_in[3];
    const float* bhr = (const float*)d_in[4];
    const float* Whz = (const float*)d_in[5];
    const float* bhz = (const float*)d_in[6];
    const float* Whn = (const float*)d_in[7];
    const float* bhn = (const float*)d_in[8];
    float* out = (float*)d_out;

    const int grid = NN / 8;   // 512 blocks x 4 waves, 8 rows/block
    attgru_fused_kernel<<<grid, 256, 0, stream>>>(x, h, adj, Whr, bhr, Whz, bhz,
                                                  Whn, bhn, out);
}

// Round 9
// 75.316 us; speedup vs baseline: 1.2845x; 1.2845x over previous
//
#include <hip/hip_runtime.h>
#include <math.h>

#define NN 4096
#define BB 8
#define NV4 (NN / 4)   // float4 per row = 1024
#define NCH 16         // chunks: lane covers idx = c*64 + lane

// Wave = 2 rows x ALL 4 gates (acc[4][2][8]); block = 4 waves = 8 rows.
// No barriers. Matrix streams (HBM-latency) register-prefetched one chunk
// ahead; x/h chunks (256 KB, L2-resident) loaded on demand.
// R7 post-mortem (rule #20): the in-wave epilogue's acc[0][r][b] with
// RUNTIME r,b forced the whole acc array into scratch (83 MB WRITE_SIZE,
// VGPR dropped to 80). Fix: post-butterfly every lane holds the complete
// sums, so lane 0 writes them to LDS with STATIC indices; lanes 0..15 then
// read runtime-indexed from LDS (legal). Same-wave LDS write->read needs
// no barrier.
__global__ __launch_bounds__(256, 2) void attgru_fused_kernel(
    const float* __restrict__ x,   const float* __restrict__ h,
    const float* __restrict__ adj, const float* __restrict__ Whr,
    const float* __restrict__ bhr, const float* __restrict__ Whz,
    const float* __restrict__ bhz, const float* __restrict__ Whn,
    const float* __restrict__ bhn, float* __restrict__ out)
{
    const int lane = threadIdx.x & 63;
    const int wave = threadIdx.x >> 6;            // 0..3
    const int row0 = blockIdx.x * 8 + wave * 2;   // 2 rows per wave

    __shared__ float red[4][4][2][BB];            // [wave][gate][row][b] 2 KB

    const float4* x4 = reinterpret_cast<const float4*>(x);
    const float4* h4 = reinterpret_cast<const float4*>(h);
    const size_t rb = (size_t)row0 * NV4;
    const float4* A = reinterpret_cast<const float4*>(adj) + rb;
    const float4* R = reinterpret_cast<const float4*>(Whr) + rb;
    const float4* Z = reinterpret_cast<const float4*>(Whz) + rb;
    const float4* G = reinterpret_cast<const float4*>(Whn) + rb;

    float acc[4][2][BB];
#pragma unroll
    for (int g = 0; g < 4; ++g)
#pragma unroll
        for (int r = 0; r < 2; ++r)
#pragma unroll
            for (int b = 0; b < BB; ++b) acc[g][r][b] = 0.f;

    // matrix regs, prefetched one chunk ahead (8 float4 = 32 VGPR)
    float4 mA[2], mR[2], mZ[2], mG[2];
#pragma unroll
    for (int r = 0; r < 2; ++r) {
        mA[r] = A[r * NV4 + lane];
        mR[r] = R[r * NV4 + lane];
        mZ[r] = Z[r * NV4 + lane];
        mG[r] = G[r * NV4 + lane];
    }

    for (int c = 0; c < NCH; ++c) {
        const int idx = c * 64 + lane;
        const bool more = (c + 1 < NCH);
        // ---- issue next chunk's matrix loads first (HBM latency path) ----
        float4 nA[2], nR[2], nZ[2], nG[2];
        if (more) {
            const int nidx = idx + 64;
#pragma unroll
            for (int r = 0; r < 2; ++r) {
                nA[r] = A[r * NV4 + nidx];
                nR[r] = R[r * NV4 + nidx];
                nZ[r] = Z[r * NV4 + nidx];
                nG[r] = G[r * NV4 + nidx];
            }
        }
        // ---- phase X: agg gate (x chunk, L2-hot) ----
#pragma unroll
        for (int b = 0; b < BB; ++b) {
            const float4 v = x4[b * NV4 + idx];
            acc[0][0][b] += mA[0].x*v.x + mA[0].y*v.y + mA[0].z*v.z + mA[0].w*v.w;
            acc[0][1][b] += mA[1].x*v.x + mA[1].y*v.y + mA[1].z*v.z + mA[1].w*v.w;
        }
        // ---- phase H: r/z/n gates (h chunk, L2-hot) ----
#pragma unroll
        for (int b = 0; b < BB; ++b) {
            const float4 v = h4[b * NV4 + idx];
            acc[1][0][b] += mR[0].x*v.x + mR[0].y*v.y + mR[0].z*v.z + mR[0].w*v.w;
            acc[1][1][b] += mR[1].x*v.x + mR[1].y*v.y + mR[1].z*v.z + mR[1].w*v.w;
            acc[2][0][b] += mZ[0].x*v.x + mZ[0].y*v.y + mZ[0].z*v.z + mZ[0].w*v.w;
            acc[2][1][b] += mZ[1].x*v.x + mZ[1].y*v.y + mZ[1].z*v.z + mZ[1].w*v.w;
            acc[3][0][b] += mG[0].x*v.x + mG[0].y*v.y + mG[0].z*v.z + mG[0].w*v.w;
            acc[3][1][b] += mG[1].x*v.x + mG[1].y*v.y + mG[1].z*v.z + mG[1].w*v.w;
        }
        // ---- rotate prefetched matrix regs ----
        if (more) {
#pragma unroll
            for (int r = 0; r < 2; ++r) {
                mA[r] = nA[r]; mR[r] = nR[r]; mZ[r] = nZ[r]; mG[r] = nG[r];
            }
        }
    }

    // full-wave butterfly: all lanes end with complete sums
#pragma unroll
    for (int off = 32; off >= 1; off >>= 1)
#pragma unroll
        for (int g = 0; g < 4; ++g)
#pragma unroll
            for (int r = 0; r < 2; ++r)
#pragma unroll
                for (int b = 0; b < BB; ++b)
                    acc[g][r][b] += __shfl_xor(acc[g][r][b], off);

    // STATIC-index LDS dump (rule #20 fix), then runtime-indexed read.
    if (lane == 0) {
#pragma unroll
        for (int g = 0; g < 4; ++g)
#pragma unroll
            for (int r = 0; r < 2; ++r)
#pragma unroll
                for (int b = 0; b < BB; ++b)
                    red[wave][g][r][b] = acc[g][r][b];
    }
    // same-wave LDS write->read: in-order within a wave, no barrier needed
    if (lane < 16) {
        const int r = lane >> 3, b = lane & 7;
        const int row = row0 + r;
        const float agg = red[wave][0][r][b];
        const float rg = 1.f / (1.f + __expf(-(agg + red[wave][1][r][b] + bhr[row])));
        const float zg = 1.f / (1.f + __expf(-(agg + red[wave][2][r][b] + bhz[row])));
        const float ng = tanhf(agg + rg * (red[wave][3][r][b] + bhn[row]));
        const float hv = h[b * NN + row];
        out[b * NN + row] = (1.f - zg) * ng + zg * hv;
    }
}

extern "C" void kernel_launch(void* const* d_in, const int* in_sizes, int n_in,
                              void* d_out, int out_size, void* d_ws, size_t ws_size,
                              hipStream_t stream) {
    const float* x   = (const float*)d_in[0];
    const float* h   = (const float*)d_in[1];
    const float* adj = (const float*)d_in[2];
    const float* Whr = (const float*)d_in[3];
    const float* bhr = (const float*)d_in[4];
    const float* Whz = (const float*)d_in[5];
    const float* bhz = (const float*)d_in[6];
    const float* Whn = (const float*)d_in[7];
    const float* bhn = (const float*)d_in[8];
    float* out = (float*)d_out;

    const int grid = NN / 8;   // 512 blocks x 4 waves, 8 rows/block
    attgru_fused_kernel<<<grid, 256, 0, stream>>>(x, h, adj, Whr, bhr, Whz, bhz,
                                                  Whn, bhn, out);
}

// Round 10
// 64.220 us; speedup vs baseline: 1.5065x; 1.1728x over previous
//
#include <hip/hip_runtime.h>
#include <math.h>

#define NN 4096
#define BB 8
#define CK 256                 // k-elements per chunk
#define NCHUNK (NN / CK)       // 16
#define ROWS 8                 // rows per block
#define CF (CK / 4)            // 64 float4 per row-chunk (1 KB)

// Direct global->LDS (no VGPR round-trip, no L1-MSHR occupancy).
// dst = wave-uniform LDS base + lane*16; src = per-lane global address.
#define GLL16(gsrc, ldst) __builtin_amdgcn_global_load_lds(                  \
    (const __attribute__((address_space(1))) void*)(gsrc),                   \
    (__attribute__((address_space(3))) void*)(ldst), 16, 0, 0)

// Block = 512 thr = 8 waves = 4 gates x 2 row-halves; 8 rows/block.
// All matrix + vector bytes stream via global_load_lds into double-buffered
// LDS (48 KB/buf); ONE __syncthreads per chunk; stage(c+1) issued BEFORE
// compute(c) so loads get the whole compute phase (~1500 cyc) to land.
// R0-R8 post-mortem: every VGPR-load structure caps at ~2.4-3.3 TB/s
// delivered (per-CU L1 miss-queue limit); gll is the proven fast path.
__global__ __launch_bounds__(512, 2) void attgru_fused_kernel(
    const float* __restrict__ x,   const float* __restrict__ h,
    const float* __restrict__ adj, const float* __restrict__ Whr,
    const float* __restrict__ bhr, const float* __restrict__ Whz,
    const float* __restrict__ bhz, const float* __restrict__ Whn,
    const float* __restrict__ bhn, float* __restrict__ out)
{
    const int t    = threadIdx.x;
    const int lane = t & 63;
    const int wave = t >> 6;        // 0..7
    const int gate = wave >> 1;     // 0:agg 1:r 2:z 3:n
    const int hf   = wave & 1;      // row-half
    const int row0 = blockIdx.x * ROWS;

    // [buf][row-mat 0..31][CF float4] : rm = gate*8 + row  (64 KB total)
    __shared__ float4 matb[2][4 * ROWS * CF];
    // [buf][x/h][batch][CF float4]                        (32 KB total)
    __shared__ float4 vecb[2][2][BB * CF];
    __shared__ float  red[8][4 * BB];                      // 1 KB

    // Wave w stages row-mats 4w..4w+3 == its own gate's rows (g = wave>>1,
    // rows hf*4..hf*4+3) -> all pointer selects are wave-uniform.
    const float* Mg = (gate == 0) ? adj : (gate == 1) ? Whr
                    : (gate == 2) ? Whz : Whn;
    const float* mrow[4];
#pragma unroll
    for (int j = 0; j < 4; ++j)
        mrow[j] = Mg + (size_t)(row0 + hf * 4 + j) * NN + lane * 4;
    // Vector jobs: waves 0-3 stage x batches {2w,2w+1}; waves 4-7 stage h.
    const float* Vg = (wave >= 4) ? h : x;
    const int vb0 = (wave & 3) * 2;
    const float* vrow[2];
#pragma unroll
    for (int j = 0; j < 2; ++j)
        vrow[j] = Vg + (size_t)(vb0 + j) * NN + lane * 4;

    const int rmbase = wave * 4;          // == gate*8 + hf*4
    const int vselw  = (wave >= 4);

#define STAGE(c, bf)                                                          \
    do {                                                                      \
        _Pragma("unroll")                                                     \
        for (int j = 0; j < 4; ++j)                                           \
            GLL16(mrow[j] + (size_t)(c) * CK,                                 \
                  &matb[bf][(rmbase + j) * CF]);                              \
        _Pragma("unroll")                                                     \
        for (int j = 0; j < 2; ++j)                                           \
            GLL16(vrow[j] + (size_t)(c) * CK,                                 \
                  &vecb[bf][vselw][(vb0 + j) * CF]);                          \
    } while (0)

    float acc[4][BB];
#pragma unroll
    for (int r = 0; r < 4; ++r)
#pragma unroll
        for (int b = 0; b < BB; ++b) acc[r][b] = 0.f;

    // prologue
    STAGE(0, 0);
    __syncthreads();

    for (int c = 0; c < NCHUNK; ++c) {
        const int cur = c & 1;
        if (c + 1 < NCHUNK) STAGE(c + 1, cur ^ 1);   // issue early

        // consume chunk c: 4 matrix + 8 vector ds_read_b128, 128 FMA
        const float4* mb = &matb[cur][(gate * 8 + hf * 4) * CF];
        const float4* vv = &vecb[cur][gate ? 1 : 0][0];
        const float4 m0 = mb[0 * CF + lane];
        const float4 m1 = mb[1 * CF + lane];
        const float4 m2 = mb[2 * CF + lane];
        const float4 m3 = mb[3 * CF + lane];
#pragma unroll
        for (int b = 0; b < BB; ++b) {
            const float4 v = vv[b * CF + lane];
            acc[0][b] += m0.x * v.x + m0.y * v.y + m0.z * v.z + m0.w * v.w;
            acc[1][b] += m1.x * v.x + m1.y * v.y + m1.z * v.z + m1.w * v.w;
            acc[2][b] += m2.x * v.x + m2.y * v.y + m2.z * v.z + m2.w * v.w;
            acc[3][b] += m3.x * v.x + m3.y * v.y + m3.z * v.z + m3.w * v.w;
        }
        __syncthreads();   // drains this chunk's gll (vmcnt0) + buffer swap
    }

    // full-wave butterfly: all lanes end with the wave's complete sums
#pragma unroll
    for (int off = 32; off >= 1; off >>= 1)
#pragma unroll
        for (int r = 0; r < 4; ++r)
#pragma unroll
            for (int b = 0; b < BB; ++b)
                acc[r][b] += __shfl_xor(acc[r][b], off);

    if (lane == 0) {
#pragma unroll
        for (int r = 0; r < 4; ++r)
#pragma unroll
            for (int b = 0; b < BB; ++b)
                red[wave][r * BB + b] = acc[r][b];
    }
    __syncthreads();

    if (t < ROWS * BB) {   // 64 outputs per block
        const int r = t >> 3, b = t & 7;
        const int wv = r >> 2, slot = (r & 3) * BB + b;
        const int row = row0 + r;
        const float agg = red[0 + wv][slot];
        const float rs  = red[2 + wv][slot];
        const float zs  = red[4 + wv][slot];
        const float ns  = red[6 + wv][slot];
        const float rg = 1.f / (1.f + __expf(-(agg + rs + bhr[row])));
        const float zg = 1.f / (1.f + __expf(-(agg + zs + bhz[row])));
        const float ng = tanhf(agg + rg * (ns + bhn[row]));
        const float hv = h[b * NN + row];
        out[b * NN + row] = (1.f - zg) * ng + zg * hv;
    }
}

extern "C" void kernel_launch(void* const* d_in, const int* in_sizes, int n_in,
                              void* d_out, int out_size, void* d_ws, size_t ws_size,
                              hipStream_t stream) {
    const float* x   = (const float*)d_in[0];
    const float* h   = (const float*)d_in[1];
    const float* adj = (const float*)d_in[2];
    const float* Whr = (const float*)d_in[3];
    const float* bhr = (const float*)d_in[4];
    const float* Whz = (const float*)d_in[5];
    const float* bhz = (const float*)d_in[6];
    const float* Whn = (const float*)d_in[7];
    const float* bhn = (const float*)d_in[8];
    float* out = (float*)d_out;

    const int grid = NN / ROWS;   // 512 blocks x 8 waves
    attgru_fused_kernel<<<grid, 512, 0, stream>>>(x, h, adj, Whr, bhr, Whz, bhz,
                                                  Whn, bhn, out);
}

// Round 11
// 60.625 us; speedup vs baseline: 1.5958x; 1.0593x over previous
//
#include <hip/hip_runtime.h>
#include <math.h>

#define NN 4096
#define BB 8
#define NV4 (NN / 4)    // float4 per row = 1024
#define CKF4 128        // float4 per chunk (512 floats)
#define NCHUNK 8
#define ROWS 16         // rows per block  -> grid = 256 = 1 block/CU
#define RPW 8           // rows per wave (its gate), split 4+4 across lane halves

// R6 structure (matrix in regs w/ rotation prefetch, vectors double-buffered
// in LDS, 8 barriers) scaled to ROWS=16. Below-L2 model from R0-R9: time ~
// (matrix 268MB + vector re-fetch nblocks*256KB) / ~7.2 TB/s. Halving the
// block count (512->256) cuts vector below-L2 traffic 134->67 MB.
// Wave = gate (wave>>1) x row-half (wave&1); lane split: lanes 0-31 handle
// rows 0-3 (of the wave's 8) at k-col (lane&31), lanes 32-63 rows 4-7.
__global__ __launch_bounds__(512, 2) void attgru_fused_kernel(
    const float* __restrict__ x,   const float* __restrict__ h,
    const float* __restrict__ adj, const float* __restrict__ Whr,
    const float* __restrict__ bhr, const float* __restrict__ Whz,
    const float* __restrict__ bhz, const float* __restrict__ Whn,
    const float* __restrict__ bhn, float* __restrict__ out)
{
    const int t    = threadIdx.x;
    const int lane = t & 63;
    const int wave = t >> 6;        // 0..7
    const int gate = wave >> 1;     // 0:agg 1:r 2:z 3:n
    const int half = wave & 1;      // row-half of the gate's 16 rows
    const int row0 = blockIdx.x * ROWS;

    __shared__ float4 vbuf[2][2][BB][CKF4];  // [buf][x/h][batch][pos] 64 KB
    __shared__ float  red[4][ROWS][BB];      // [gate][row][batch] 2 KB

    const float* Msel = (gate == 0) ? adj : (gate == 1) ? Whr
                      : (gate == 2) ? Whz : Whn;
    const int vsel = (gate != 0);
    const int rsub = (lane >> 5) * 4;        // 0 or 4: which 4-row group
    const int kl   = lane & 31;              // k-col within 32-f4 sub-pass
    const float4* M4 = reinterpret_cast<const float4*>(Msel)
                     + (size_t)(row0 + half * RPW + rsub) * NV4;

    const float4* x4 = reinterpret_cast<const float4*>(x);
    const float4* h4 = reinterpret_cast<const float4*>(h);
    const int sb = t >> 6, sl = t & 63;      // staging: batch sb, pos sl/sl+64
    const float4* srcx = x4 + sb * NV4;
    const float4* srch = h4 + sb * NV4;

    // ---- prologue: stage vector chunk 0; matrix regs for q=0 ----
    vbuf[0][0][sb][sl]      = srcx[sl];
    vbuf[0][0][sb][sl + 64] = srcx[sl + 64];
    vbuf[0][1][sb][sl]      = srch[sl];
    vbuf[0][1][sb][sl + 64] = srch[sl + 64];
    float4 mc0 = M4[0 * NV4 + kl];
    float4 mc1 = M4[1 * NV4 + kl];
    float4 mc2 = M4[2 * NV4 + kl];
    float4 mc3 = M4[3 * NV4 + kl];
    __syncthreads();

    float acc[4][BB];
#pragma unroll
    for (int r = 0; r < 4; ++r)
#pragma unroll
        for (int b = 0; b < BB; ++b) acc[r][b] = 0.f;

    for (int c = 0; c < NCHUNK; ++c) {
        const int cur = c & 1;
        const bool more = (c + 1 < NCHUNK);
        // issue next vector chunk early (longest path: maybe-L3 -> LDS)
        float4 rx0, rx1, rh0, rh1;
        if (more) {
            const int vb = (c + 1) * CKF4;
            rx0 = srcx[vb + sl];  rx1 = srcx[vb + sl + 64];
            rh0 = srch[vb + sl];  rh1 = srch[vb + sl + 64];
        }
        // 4 sub-passes; matrix regs rotate one sub-pass ahead (static names)
#pragma unroll
        for (int p = 0; p < 4; ++p) {
            const int q = c * 4 + p;
            float4 mn0, mn1, mn2, mn3;
            if (q + 1 < 32) {
                const int nc = (q + 1) * 32 + kl;
                mn0 = M4[0 * NV4 + nc];  mn1 = M4[1 * NV4 + nc];
                mn2 = M4[2 * NV4 + nc];  mn3 = M4[3 * NV4 + nc];
            }
            const int vk = p * 32 + kl;
#pragma unroll
            for (int b = 0; b < BB; ++b) {
                const float4 v = vbuf[cur][vsel][b][vk];  // broadcast pairs
                acc[0][b] += mc0.x*v.x + mc0.y*v.y + mc0.z*v.z + mc0.w*v.w;
                acc[1][b] += mc1.x*v.x + mc1.y*v.y + mc1.z*v.z + mc1.w*v.w;
                acc[2][b] += mc2.x*v.x + mc2.y*v.y + mc2.z*v.z + mc2.w*v.w;
                acc[3][b] += mc3.x*v.x + mc3.y*v.y + mc3.z*v.z + mc3.w*v.w;
            }
            if (q + 1 < 32) { mc0 = mn0; mc1 = mn1; mc2 = mn2; mc3 = mn3; }
        }
        if (more) {
            vbuf[cur ^ 1][0][sb][sl]      = rx0;
            vbuf[cur ^ 1][0][sb][sl + 64] = rx1;
            vbuf[cur ^ 1][1][sb][sl]      = rh0;
            vbuf[cur ^ 1][1][sb][sl + 64] = rh1;
        }
        __syncthreads();
    }

    // reduce over the 32 k-lanes of each half (offsets 1..16)
#pragma unroll
    for (int off = 1; off <= 16; off <<= 1)
#pragma unroll
        for (int r = 0; r < 4; ++r)
#pragma unroll
            for (int b = 0; b < BB; ++b)
                acc[r][b] += __shfl_xor(acc[r][b], off);

    // lanes 0 and 32 hold complete sums for their 4-row groups (static dump)
    if (lane == 0) {
#pragma unroll
        for (int r = 0; r < 4; ++r)
#pragma unroll
            for (int b = 0; b < BB; ++b)
                red[gate][half * RPW + r][b] = acc[r][b];
    } else if (lane == 32) {
#pragma unroll
        for (int r = 0; r < 4; ++r)
#pragma unroll
            for (int b = 0; b < BB; ++b)
                red[gate][half * RPW + 4 + r][b] = acc[r][b];
    }
    __syncthreads();

    if (t < ROWS * BB) {   // 128 outputs per block
        const int r = t >> 3, b = t & 7;
        const int row = row0 + r;
        const float agg = red[0][r][b];
        const float rg = 1.f / (1.f + __expf(-(agg + red[1][r][b] + bhr[row])));
        const float zg = 1.f / (1.f + __expf(-(agg + red[2][r][b] + bhz[row])));
        const float ng = tanhf(agg + rg * (red[3][r][b] + bhn[row]));
        const float hv = h[b * NN + row];
        out[b * NN + row] = (1.f - zg) * ng + zg * hv;
    }
}

extern "C" void kernel_launch(void* const* d_in, const int* in_sizes, int n_in,
                              void* d_out, int out_size, void* d_ws, size_t ws_size,
                              hipStream_t stream) {
    const float* x   = (const float*)d_in[0];
    const float* h   = (const float*)d_in[1];
    const float* adj = (const float*)d_in[2];
    const float* Whr = (const float*)d_in[3];
    const float* bhr = (const float*)d_in[4];
    const float* Whz = (const float*)d_in[5];
    const float* bhz = (const float*)d_in[6];
    const float* Whn = (const float*)d_in[7];
    const float* bhn = (const float*)d_in[8];
    float* out = (float*)d_out;

    const int grid = NN / ROWS;   // 256 blocks x 8 waves, 1 block/CU
    attgru_fused_kernel<<<grid, 512, 0, stream>>>(x, h, adj, Whr, bhr, Whz, bhz,
                                                  Whn, bhn, out);
}

// Round 12
// 57.461 us; speedup vs baseline: 1.6837x; 1.0551x over previous
//
#include <hip/hip_runtime.h>
#include <math.h>

#define NN 4096
#define BB 8
#define NV4 (NN / 4)        // float4 per row = 1024
#define CF4 128             // float4 per K-chunk (512 floats), 2 sub-passes
#define NCHUNK (NV4 / CF4)  // 8
#define ROWS 8              // rows per block
#define RPW 4               // rows per wave

// Clang ext-vector so __builtin_nontemporal_load works on 16-B loads.
typedef float v4 __attribute__((ext_vector_type(4)));

// R6 champion structure (55.9 us) + ONE change: matrix loads are
// NON-TEMPORAL (read-once stream; nt flag -> lowest cache-reuse priority,
// don't churn L1/L2 against the cache-hot x/h vectors).
// R0-R10 post-mortem: occupancy/barriers/residency/load-path all invariant;
// the limiter is the 268 MB matrix stream at ~4.8 TB/s effective (50% L3).
__global__ __launch_bounds__(512, 2) void attgru_fused_kernel(
    const float* __restrict__ x,   const float* __restrict__ h,
    const float* __restrict__ adj, const float* __restrict__ Whr,
    const float* __restrict__ bhr, const float* __restrict__ Whz,
    const float* __restrict__ bhz, const float* __restrict__ Whn,
    const float* __restrict__ bhn, float* __restrict__ out)
{
    const int t    = threadIdx.x;
    const int lane = t & 63;
    const int wave = t >> 6;      // 0..7
    const int gate = wave >> 1;   // 0:agg 1:r 2:z 3:n
    const int rg   = wave & 1;    // row-group
    const int row0 = blockIdx.x * ROWS;

    __shared__ float4 vbuf[2][2][BB][CF4];  // [buf][x/h][batch][pos] 64 KB
    __shared__ float  red[8][RPW * BB];     // per-wave complete sums, 1 KB

    const float* Msel = (gate == 0) ? adj : (gate == 1) ? Whr
                      : (gate == 2) ? Whz : Whn;
    const int vsel = (gate != 0);
    const v4* M4 = reinterpret_cast<const v4*>(Msel)
                 + (size_t)(row0 + rg * RPW) * NV4;
    const float4* x4 = reinterpret_cast<const float4*>(x);
    const float4* h4 = reinterpret_cast<const float4*>(h);

    // Stage mapping: thread t stages batch (t>>6), positions sl and sl+64.
    const int sb = t >> 6, sl = t & 63;
    const float4* srcx = x4 + sb * NV4;
    const float4* srch = h4 + sb * NV4;

    // ---- prologue: stage chunk 0, load matrix sub0 of chunk 0 ----
    v4 mc[RPW];
#pragma unroll
    for (int r = 0; r < RPW; ++r)
        mc[r] = __builtin_nontemporal_load(&M4[r * NV4 + lane]);
    {
        const float4 a0 = srcx[sl],      a1 = srcx[sl + 64];
        const float4 b0 = srch[sl],      b1 = srch[sl + 64];
        vbuf[0][0][sb][sl]      = a0;
        vbuf[0][0][sb][sl + 64] = a1;
        vbuf[0][1][sb][sl]      = b0;
        vbuf[0][1][sb][sl + 64] = b1;
    }
    __syncthreads();

    float acc[RPW][BB];
#pragma unroll
    for (int r = 0; r < RPW; ++r)
#pragma unroll
        for (int b = 0; b < BB; ++b) acc[r][b] = 0.f;

    for (int c = 0; c < NCHUNK; ++c) {
        const int cur = c & 1, nxt = cur ^ 1;
        const bool more = (c + 1 < NCHUNK);

        // issue next-chunk vector loads (normal/cached: x/h are reused)
        float4 rx0, rx1, rh0, rh1;
        if (more) {
            const int vc = (c + 1) * CF4;
            rx0 = srcx[vc + sl];  rx1 = srcx[vc + sl + 64];
            rh0 = srch[vc + sl];  rh1 = srch[vc + sl + 64];
        }
        // matrix regs for sub1 of this chunk (nt: read-once stream)
        v4 mn[RPW];
#pragma unroll
        for (int r = 0; r < RPW; ++r)
            mn[r] = __builtin_nontemporal_load(
                        &M4[r * NV4 + c * CF4 + 64 + lane]);

        // ---- sub-pass 0: positions [0,64) ----
#pragma unroll
        for (int b = 0; b < BB; ++b) {
            const float4 vb = vbuf[cur][vsel][b][lane];
#pragma unroll
            for (int r = 0; r < RPW; ++r)
                acc[r][b] += mc[r].x * vb.x + mc[r].y * vb.y
                           + mc[r].z * vb.z + mc[r].w * vb.w;
        }

        // prefetch matrix sub0 of next chunk (nt)
        v4 mc2[RPW];
        if (more) {
#pragma unroll
            for (int r = 0; r < RPW; ++r)
                mc2[r] = __builtin_nontemporal_load(
                             &M4[r * NV4 + (c + 1) * CF4 + lane]);
        }

        // ---- sub-pass 1: positions [64,128) ----
#pragma unroll
        for (int b = 0; b < BB; ++b) {
            const float4 vb = vbuf[cur][vsel][b][64 + lane];
#pragma unroll
            for (int r = 0; r < RPW; ++r)
                acc[r][b] += mn[r].x * vb.x + mn[r].y * vb.y
                           + mn[r].z * vb.z + mn[r].w * vb.w;
        }

        if (more) {
            vbuf[nxt][0][sb][sl]      = rx0;
            vbuf[nxt][0][sb][sl + 64] = rx1;
            vbuf[nxt][1][sb][sl]      = rh0;
            vbuf[nxt][1][sb][sl + 64] = rh1;
#pragma unroll
            for (int r = 0; r < RPW; ++r) mc[r] = mc2[r];
            __syncthreads();
        }
    }

    // full-wave butterfly: all lanes end with the wave's complete sums
#pragma unroll
    for (int off = 32; off >= 1; off >>= 1)
#pragma unroll
        for (int r = 0; r < RPW; ++r)
#pragma unroll
            for (int b = 0; b < BB; ++b)
                acc[r][b] += __shfl_xor(acc[r][b], off);

    if (lane == 0) {
#pragma unroll
        for (int r = 0; r < RPW; ++r)
#pragma unroll
            for (int b = 0; b < BB; ++b)
                red[wave][r * BB + b] = acc[r][b];
    }
    __syncthreads();

    if (t < ROWS * BB) {   // 64 outputs per block
        const int r = t >> 3, b = t & 7;
        const int rgg = r >> 2, idx = (r & 3) * BB + b;
        const int row = row0 + r;
        const float agg = red[0 * 2 + rgg][idx];
        const float rs  = red[1 * 2 + rgg][idx];
        const float zs  = red[2 * 2 + rgg][idx];
        const float ns  = red[3 * 2 + rgg][idx];
        const float rgt = 1.f / (1.f + __expf(-(agg + rs + bhr[row])));
        const float zgt = 1.f / (1.f + __expf(-(agg + zs + bhz[row])));
        const float ngt = tanhf(agg + rgt * (ns + bhn[row]));
        const float hv  = h[b * NN + row];
        out[b * NN + row] = (1.f - zgt) * ngt + zgt * hv;
    }
}

extern "C" void kernel_launch(void* const* d_in, const int* in_sizes, int n_in,
                              void* d_out, int out_size, void* d_ws, size_t ws_size,
                              hipStream_t stream) {
    const float* x   = (const float*)d_in[0];
    const float* h   = (const float*)d_in[1];
    const float* adj = (const float*)d_in[2];
    const float* Whr = (const float*)d_in[3];
    const float* bhr = (const float*)d_in[4];
    const float* Whz = (const float*)d_in[5];
    const float* bhz = (const float*)d_in[6];
    const float* Whn = (const float*)d_in[7];
    const float* bhn = (const float*)d_in[8];
    float* out = (float*)d_out;

    const int grid = NN / ROWS;   // 512 blocks x 8 waves
    attgru_fused_kernel<<<grid, 512, 0, stream>>>(x, h, adj, Whr, bhr, Whz, bhz,
                                                  Whn, bhn, out);
}